// Round 7
// baseline (281.327 us; speedup 1.0000x reference)
//
#include <hip/hip_runtime.h>

#define INPUT 32
#define HIDDEN 64
#define BATCH 4096
#define SEQ 256
#define CHT 16                 // timesteps per chunk
#define NCH (SEQ / CHT)        // 16 chunks

typedef __attribute__((ext_vector_type(8))) short bf16x8;   // 8 bf16 (4 VGPRs)
typedef __attribute__((ext_vector_type(4))) float floatx4;  // 4 fp32

#define MFMA(a, b, c) __builtin_amdgcn_mfma_f32_16x16x32_bf16((a), (b), (c), 0, 0, 0)

// RNE f32->bf16 scalar (setup-only).
__device__ __forceinline__ unsigned short f2bf(float f) {
    unsigned u = __float_as_uint(f);
    u += 0x7fffu + ((u >> 16) & 1u);
    return (unsigned short)(u >> 16);
}
__device__ __forceinline__ float bf2f(unsigned short b) {
    return __uint_as_float(((unsigned)b) << 16);
}
__device__ __forceinline__ void split8(const float f[8], bf16x8& hi, bf16x8& lo) {
#pragma unroll
    for (int j = 0; j < 8; ++j) {
        unsigned short h = f2bf(f[j]);
        hi[j] = (short)h;
        lo[j] = (short)f2bf(f[j] - bf2f(h));
    }
}

// Truncation split of a pair -> packed hi/lo words. Used for x.
__device__ __forceinline__ void packpair(float f0, float f1, unsigned& hw, unsigned& lw) {
    unsigned b0 = __float_as_uint(f0), b1 = __float_as_uint(f1);
    float h0 = __uint_as_float(b0 & 0xffff0000u);
    float h1 = __uint_as_float(b1 & 0xffff0000u);
    float l0 = f0 - h0, l1 = f1 - h1;
    hw = __builtin_amdgcn_perm(b1, b0, 0x07060302u);
    lw = __builtin_amdgcn_perm(__float_as_uint(l1), __float_as_uint(l0), 0x07060302u);
}

// RNE pack of a pair (recurrent state: accuracy matters).
__device__ __forceinline__ unsigned pack_rne(float f0, float f1) {
    unsigned r0 = __float_as_uint(f0);
    r0 += 0x7fffu + ((r0 >> 16) & 1u);
    unsigned r1 = __float_as_uint(f1);
    r1 += 0x7fffu + ((r1 >> 16) & 1u);
    return __builtin_amdgcn_perm(r1, r0, 0x07060302u);
}

union FragU { bf16x8 v; unsigned u[4]; };

__device__ __forceinline__ void pack8(float4 a, float4 b, FragU& H, FragU& L) {
    packpair(a.x, a.y, H.u[0], L.u[0]);
    packpair(a.z, a.w, H.u[1], L.u[1]);
    packpair(b.x, b.y, H.u[2], L.u[2]);
    packpair(b.z, b.w, H.u[3], L.u[3]);
}

// Round-19: producer/consumer split. Evidence chain:
//  - r12/r16/r18: the per-step 4-wave barrier'd LDS exchange has a fixed
//    ~1100cy structural cost (stripping 60% of in-loop issue saved only
//    110cy/step). The exchange must GO, not shrink.
//  - r15 (HW-verified, bit-exact): the D->B relabeling keeps the whole
//    recurrence in ONE wave's registers; its 2030cy/step was single-wave
//    ISSUE cost, ~60% of it ih/x work that doesn't depend on h.
//  - r18 (HW-verified, bit-exact): ih can detour through f32 LDS exactly.
// Structure: wave 0 = consumer, runs the recurrence in registers (r15
// relabeled Whh, 16 MFMA + 16-elem tanh + pack per step; h never touches
// LDS; NO barriers in the step loop). Waves 1-3 = producers, compute
// ih = x.W_ih^T + b_ih + b_hh (r18 phase-A verbatim) one 16-step chunk
// ahead into a double-buffered 128 KiB LDS buffer. One __syncthreads per
// chunk (17 total vs 256 in r18). All components bit-identical to verified
// predecessors -> absmax must reproduce 0.00390625 exactly.
// Layouts (HW-verified r5-r18): C/D row(m)=4qd+r, col(n)=ln. A: m=ln,
//   k=8qd+j. B: n=ln, k=8qd+j (+32/frag). Relabel sigma absorbed into Whh
//   COLUMN order: frag fT cols [32fT+4qd,+4) and [32fT+16+4qd,+4) of row
//   16mt+ln. W_ih/x/biases/W_fc natural. IH[buf][s][mt][lane*4+r] f32.
__global__ __launch_bounds__(256, 1) void rnn_pc_kernel(
    const float* __restrict__ x,     // [B, T, 32]
    const float* __restrict__ W_ih,  // [64, 32]
    const float* __restrict__ W_hh,  // [64, 64]
    const float* __restrict__ b_ih,  // [64]
    const float* __restrict__ b_hh,  // [64]
    const float* __restrict__ W_fc,  // [1, 64]
    const float* __restrict__ b_fc,  // [1]
    float* __restrict__ out)         // [B, 1]
{
    const int tid  = threadIdx.x;
    const int nt   = tid >> 6;        // 0 = consumer; 1..3 = producers
    const int lane = tid & 63;
    const int ln   = lane & 15;       // batch column
    const int qd   = lane >> 4;
    const int b0   = blockIdx.x * 16;

    __shared__ __align__(16) float IH[2][CHT][4][256];   // 128 KiB, dbuf

    if (nt == 0) {
        // ================== CONSUMER ==================
        // Whh (relabeled columns), hi/lo split — r15 verbatim.
        bf16x8 WhhH[4][2], WhhL[4][2];
#pragma unroll
        for (int mt = 0; mt < 4; ++mt) {
            float f[8];
            const float* rh = W_hh + (mt * 16 + ln) * HIDDEN;
#pragma unroll
            for (int fT = 0; fT < 2; ++fT) {
                *(float4*)&f[0] = *(const float4*)(rh + fT * 32 + qd * 4);
                *(float4*)&f[4] = *(const float4*)(rh + fT * 32 + 16 + qd * 4);
                split8(f, WhhH[mt][fT], WhhL[mt][fT]);
            }
        }

        __syncthreads();   // chunk 0 of IH published by producers

        bf16x8 g0 = {0, 0, 0, 0, 0, 0, 0, 0};   // h_{-1} = 0
        bf16x8 g1 = {0, 0, 0, 0, 0, 0, 0, 0};
        floatx4 d[4];      // this wave's h rows (f32); live for the head
        floatx4 ih[4];
#pragma unroll
        for (int mt = 0; mt < 4; ++mt)
            ih[mt] = *(const floatx4*)&IH[0][0][mt][lane * 4];

#pragma unroll 1
        for (int c = 0; c < NCH; ++c) {
#pragma unroll
            for (int s = 0; s < CHT; ++s) {
                // Prefetch ihacc for s+1 (plenty of slack under the MFMAs).
                floatx4 nih[4];
                if (s + 1 < CHT) {
#pragma unroll
                    for (int mt = 0; mt < 4; ++mt)
                        nih[mt] = *(const floatx4*)&IH[c & 1][s + 1][mt][lane * 4];
                }

                // hh: depth-2 hi chain + parallel depth-2 lo chain per tile
                // (8 independent chains -> good single-wave ILP). r15 order.
#pragma unroll
                for (int mt = 0; mt < 4; ++mt) {
                    floatx4 a = MFMA(WhhH[mt][0], g0, ih[mt]);
                    a = MFMA(WhhH[mt][1], g1, a);
                    floatx4 cc = {0.f, 0.f, 0.f, 0.f};
                    cc = MFMA(WhhL[mt][0], g0, cc);
                    cc = MFMA(WhhL[mt][1], g1, cc);
#pragma unroll
                    for (int r = 0; r < 4; ++r) {
                        float p = a[r] + cc[r];
                        float e = __expf(2.0f * p);
                        d[mt][r] = 1.0f - 2.0f * __builtin_amdgcn_rcpf(e + 1.0f);
                    }
                }

                // D -> B-frag pack (relabeled space) — r15 verbatim.
                FragU G0, G1;
                G0.u[0] = pack_rne(d[0][0], d[0][1]);
                G0.u[1] = pack_rne(d[0][2], d[0][3]);
                G0.u[2] = pack_rne(d[1][0], d[1][1]);
                G0.u[3] = pack_rne(d[1][2], d[1][3]);
                G1.u[0] = pack_rne(d[2][0], d[2][1]);
                G1.u[1] = pack_rne(d[2][2], d[2][3]);
                G1.u[2] = pack_rne(d[3][0], d[3][1]);
                G1.u[3] = pack_rne(d[3][2], d[3][3]);
                g0 = G0.v;
                g1 = G1.v;

                if (s + 1 < CHT) {
#pragma unroll
                    for (int mt = 0; mt < 4; ++mt) ih[mt] = nih[mt];
                }
            }
            __syncthreads();   // next chunk published; this buffer reusable
            if (c + 1 < NCH) {
#pragma unroll
                for (int mt = 0; mt < 4; ++mt)
                    ih[mt] = *(const floatx4*)&IH[(c + 1) & 1][0][mt][lane * 4];
            }
        }

        // ---- Head: out[b] = sum_p Wfc[p] h[p][b] + b_fc — r15 verbatim ----
        float acc = 0.f;
#pragma unroll
        for (int mt = 0; mt < 4; ++mt) {
            float4 wf = *(const float4*)(W_fc + mt * 16 + qd * 4);
            acc += wf.x * d[mt][0] + wf.y * d[mt][1] +
                   wf.z * d[mt][2] + wf.w * d[mt][3];
        }
        acc += __shfl_xor(acc, 16, 64);
        acc += __shfl_xor(acc, 32, 64);
        if (lane < 16) out[b0 + lane] = acc + b_fc[0];
    } else {
        // ================== PRODUCERS (waves 1..3) ==================
        // W_ih hi/lo + fused bias — r18 phase-A verbatim (natural order).
        bf16x8 WihH4[4], WihL4[4];
        floatx4 bbv4[4];
#pragma unroll
        for (int mt = 0; mt < 4; ++mt) {
            float f[8];
            const float* ri = W_ih + (mt * 16 + ln) * INPUT + qd * 8;
            *(float4*)&f[0] = *(const float4*)ri;
            *(float4*)&f[4] = *(const float4*)(ri + 4);
            split8(f, WihH4[mt], WihL4[mt]);
            float4 bi = *(const float4*)(b_ih + mt * 16 + qd * 4);
            float4 bh = *(const float4*)(b_hh + mt * 16 + qd * 4);
            bbv4[mt][0] = bi.x + bh.x; bbv4[mt][1] = bi.y + bh.y;
            bbv4[mt][2] = bi.z + bh.z; bbv4[mt][3] = bi.w + bh.w;
        }
        const float* xp = x + (size_t)(b0 + ln) * (SEQ * INPUT) + qd * 8;

        // Prologue: fill chunk 0 (stripes across waves 1..3).
#pragma unroll 1
        for (int i = nt - 1; i < CHT; i += 3) {
            float4 ra = *(const float4*)(xp + i * INPUT);
            float4 rb = *(const float4*)(xp + i * INPUT + 4);
            FragU H, L;
            pack8(ra, rb, H, L);
#pragma unroll
            for (int mt = 0; mt < 4; ++mt) {
                floatx4 ihv = MFMA(WihH4[mt], H.v, bbv4[mt]);
                ihv = MFMA(WihH4[mt], L.v, ihv);
                ihv = MFMA(WihL4[mt], H.v, ihv);
                *(floatx4*)&IH[0][i][mt][lane * 4] = ihv;
            }
        }
        __syncthreads();   // chunk 0 published

#pragma unroll 1
        for (int c = 0; c < NCH; ++c) {
            if (c + 1 < NCH) {
                const int base = (c + 1) * CHT;
#pragma unroll 1
                for (int i = nt - 1; i < CHT; i += 3) {
                    const int t = base + i;
                    float4 ra = *(const float4*)(xp + t * INPUT);
                    float4 rb = *(const float4*)(xp + t * INPUT + 4);
                    FragU H, L;
                    pack8(ra, rb, H, L);
#pragma unroll
                    for (int mt = 0; mt < 4; ++mt) {
                        floatx4 ihv = MFMA(WihH4[mt], H.v, bbv4[mt]);
                        ihv = MFMA(WihH4[mt], L.v, ihv);
                        ihv = MFMA(WihL4[mt], H.v, ihv);
                        *(floatx4*)&IH[(c + 1) & 1][i][mt][lane * 4] = ihv;
                    }
                }
            }
            __syncthreads();   // matches consumer's per-chunk barrier
        }
    }
}

extern "C" void kernel_launch(void* const* d_in, const int* in_sizes, int n_in,
                              void* d_out, int out_size, void* d_ws, size_t ws_size,
                              hipStream_t stream) {
    const float* x    = (const float*)d_in[0];
    const float* W_ih = (const float*)d_in[1];
    const float* W_hh = (const float*)d_in[2];
    const float* b_ih = (const float*)d_in[3];
    const float* b_hh = (const float*)d_in[4];
    const float* W_fc = (const float*)d_in[5];
    const float* b_fc = (const float*)d_in[6];
    float* out = (float*)d_out;

    // 256 groups of 16 chains: 4 waves each (1 consumer + 3 producers),
    // one group per CU.
    rnn_pc_kernel<<<dim3(BATCH / 16), dim3(256), 0, stream>>>(
        x, W_ih, W_hh, b_ih, b_hh, W_fc, b_fc, out);
}

// Round 9
// 253.451 us; speedup vs baseline: 1.1100x; 1.1100x over previous
//
#include <hip/hip_runtime.h>

#define INPUT 32
#define HIDDEN 64
#define BATCH 4096
#define SEQ 256
#define CHT 32   // timesteps per chunk (LDS ih buffer)

typedef __attribute__((ext_vector_type(8))) _Float16 f16x8;   // 8 fp16 (4 VGPRs)
typedef __attribute__((ext_vector_type(2))) __fp16 cvt2_t;    // cvt_pkrtz result
typedef __attribute__((ext_vector_type(4))) float floatx4;    // 4 fp32

#define MFMA16(a, b, c) __builtin_amdgcn_mfma_f32_16x16x32_f16((a), (b), (c), 0, 0, 0)

// LDS-only barrier: wait LDS ops, leave global loads in flight.
#define LDS_BARRIER() asm volatile("s_waitcnt lgkmcnt(0)\n\ts_barrier" ::: "memory")

union FragH { f16x8 v; unsigned u[4]; unsigned short s[8]; };

// v_cvt_pkrtz_f16_f32: packs (a,b) -> (lo,hi) fp16 RTZ, as a u32 word.
__device__ __forceinline__ unsigned pkrtz(float a, float b) {
    cvt2_t r = __builtin_amdgcn_cvt_pkrtz(a, b);
    union { cvt2_t v; unsigned u; } c; c.v = r; return c.u;
}

// f32 -> fp16 RNE (setup-only, for weights).
__device__ __forceinline__ unsigned short f2h(float f) {
    _Float16 h = (_Float16)f;                 // v_cvt_f16_f32, RNE
    union { _Float16 h; unsigned short s; } c; c.h = h; return c.s;
}
__device__ __forceinline__ void cvt8(const float f[8], FragH& out) {
#pragma unroll
    for (int j = 0; j < 8; ++j) out.s[j] = f2h(f[j]);
}

// Round-21 = Round-20 with the cvt_pkrtz type fix (clang: builtin returns
// __fp16 vector, not _Float16 vector; bit-cast through a union).
// Design (r20): fp16 swap of r18 (best verified base, 130us/dispatch).
// r19 post-mortem: wall tracks PER-WAVE issue volume on a fixed latency
// term; r18's 4-wave split + hoisted ih is the best structure found. This
// round halves critical-path arithmetic inside it: bf16 hi/lo (7-bit
// mantissa workaround) -> single fp16 (11 bits; more accurate than the
// hi/lo pair; all values in range: |h|<=1, |x|<~5, |W|<=0.125).
//   Phase B: 4 MFMA -> 2 (WhhL chain + a+c add GONE), pack 6 VALU -> 2
//     pkrtz. Exchange/barrier structure untouched.
//   Phase A: 12 MFMA -> 4 per t, x-pack 24 VALU -> 4 pkrtz.
// mfma_f32_16x16x32_f16 has the IDENTICAL fragment layout as the bf16 one
// (C/D layout dtype-independent on gfx950) -> all verified G/IH addressing
// (r5-r18) drops in. h packed RTZ (err 2^-11, 4x better than bf16 RNE) ->
// absmax predicted to IMPROVE below 0.0039; if absmax > 0.01, mis-wired.
// Layouts (verified r5-r18): C/D row(m)=4qd+r, col(n)=ln. A: m=ln, k=8qd+j
//   (+32kt). B: n=ln, k=8qd+j (+32kt). G in LDS (u16 payload, now fp16):
//   buf*1024 + kt*512 + ln*32 + slot*8 + j, slot=(qd+(ln>>1))&3.
// IH layout: IH[s][mt][(qd*16+ln)*4 + r] f32 (exact detour, r18-verified).
__global__ __launch_bounds__(256, 1) void rnn_2ph16_kernel(
    const float* __restrict__ x,     // [B, T, 32]
    const float* __restrict__ W_ih,  // [64, 32]
    const float* __restrict__ W_hh,  // [64, 64]
    const float* __restrict__ b_ih,  // [64]
    const float* __restrict__ b_hh,  // [64]
    const float* __restrict__ W_fc,  // [1, 64]
    const float* __restrict__ b_fc,  // [1]
    float* __restrict__ out)         // [B, 1]
{
    const int tid  = threadIdx.x;
    const int nt   = tid >> 6;        // wave id: owns hidden rows [16nt, 16nt+16)
    const int lane = tid & 63;
    const int ln   = lane & 15;
    const int qd   = lane >> 4;
    const int b0   = blockIdx.x * 16;

    __shared__ __align__(16) float IH[CHT][4][256];         // 128 KiB ih buffer
    __shared__ __align__(16) unsigned short Gs[2048];       // 4 KiB: 2 bufs
    __shared__ float Ps[64];

    { // zero G buffer 0 (h_{-1} = 0); visible after first phase-A sync
        unsigned* z = (unsigned*)Gs;
        for (int i = tid; i < 512; i += 256) z[i] = 0u;
    }

    // ---- Static weights (fp16 RNE) ----
    // Full W_ih (all 4 tiles) for phase A; own-tile W_hh for phase B.
    FragH WihF[4], WhhF[2];
    floatx4 bbv4[4];
    {
        float f[8];
#pragma unroll
        for (int mt = 0; mt < 4; ++mt) {
            const float* ri = W_ih + (mt * 16 + ln) * INPUT + qd * 8;
            *(float4*)&f[0] = *(const float4*)ri;
            *(float4*)&f[4] = *(const float4*)(ri + 4);
            cvt8(f, WihF[mt]);
            float4 bi = *(const float4*)(b_ih + mt * 16 + qd * 4);
            float4 bh = *(const float4*)(b_hh + mt * 16 + qd * 4);
            bbv4[mt][0] = bi.x + bh.x; bbv4[mt][1] = bi.y + bh.y;
            bbv4[mt][2] = bi.z + bh.z; bbv4[mt][3] = bi.w + bh.w;
        }
        const float* rh = W_hh + (nt * 16 + ln) * HIDDEN + qd * 8;
#pragma unroll
        for (int kt = 0; kt < 2; ++kt) {
            *(float4*)&f[0] = *(const float4*)(rh + kt * 32);
            *(float4*)&f[4] = *(const float4*)(rh + kt * 32 + 4);
            cvt8(f, WhhF[kt]);
        }
    }
    const int u0 = nt * 16 + qd * 4;   // this lane's 4 output rows (phase B)
    floatx4 wfcv;
    {
        float4 wf = *(const float4*)(W_fc + u0);
        wfcv[0] = wf.x; wfcv[1] = wf.y; wfcv[2] = wf.z; wfcv[3] = wf.w;
    }

    // Exchange bases (r12/r18, verified): reader (B-frag) and writer.
    const int rbase = ln * 32 + ((qd + (ln >> 1)) & 3) * 8;
    const int wbase = (u0 >> 5) * 512 + ln * 32 +
                      ((((u0 >> 3) & 3) + (ln >> 1)) & 3) * 8 + (u0 & 7);

    const float* xp = x + (size_t)(b0 + ln) * (SEQ * INPUT) + qd * 8;
    const int ihoff = (qd * 16 + ln) * 4;   // this lane's float4 in a slab

    f16x8 g0, g1;
    floatx4 ihacc;
    float hv[4];

#pragma unroll 1
    for (int cb = 0; cb < SEQ; cb += CHT) {
        // ================= Phase A: ih for t in [cb, cb+CHT) =================
        {
            const int tbase = cb + nt * (CHT / 4);
#pragma unroll
            for (int i = 0; i < CHT / 4; ++i) {
                const int t = tbase + i;
                float4 ra = *(const float4*)(xp + t * INPUT);
                float4 rb = *(const float4*)(xp + t * INPUT + 4);
                FragH X;
                X.u[0] = pkrtz(ra.x, ra.y);
                X.u[1] = pkrtz(ra.z, ra.w);
                X.u[2] = pkrtz(rb.x, rb.y);
                X.u[3] = pkrtz(rb.z, rb.w);
#pragma unroll
                for (int mt = 0; mt < 4; ++mt) {
                    floatx4 ih = MFMA16(WihF[mt].v, X.v, bbv4[mt]);
                    *(floatx4*)&IH[t - cb][mt][ihoff] = ih;
                }
            }
        }
        __syncthreads();   // IH chunk + (first iter) zero-init visible

        if (cb == 0) {     // initial g = h_{-1} = 0 from G buffer 0
            g0 = *(const f16x8*)(Gs + rbase);
            g1 = *(const f16x8*)(Gs + rbase + 512);
        }
        ihacc = *(const floatx4*)&IH[0][nt][ihoff];

        // ================= Phase B: 32 serial steps =================
#pragma unroll 1
        for (int sb = 0; sb < CHT; sb += 2) {
#pragma unroll
            for (int p = 0; p < 2; ++p) {
                const int s = sb + p;   // parity p == s&1 (t = cb+s, cb%32==0)

                // hh critical path: single fp16 depth-2 chain (no lo chain).
                floatx4 a = MFMA16(WhhF[0].v, g0, ihacc);
                a = MFMA16(WhhF[1].v, g1, a);

                // tanh of this wave's 4 elements.
#pragma unroll
                for (int r = 0; r < 4; ++r) {
                    float pv = a[r];
                    float e = __expf(2.0f * pv);
                    hv[r] = 1.0f - 2.0f * __builtin_amdgcn_rcpf(e + 1.0f);
                }

                // Pack 4 -> 2 u32 (pkrtz: f0 low, f1 high — same word order
                // as the verified bf16 pack), ONE ds_write_b64.
                uint2 wv;
                wv.x = pkrtz(hv[0], hv[1]);
                wv.y = pkrtz(hv[2], hv[3]);
                *(uint2*)(Gs + ((p ^ 1) << 10) + wbase) = wv;

                LDS_BARRIER();   // publish h_t; nothing else on lgkm queue

                // Prefetch g for t+1 and ihacc for s+1.
                // (s==31: IH read is stale/garbage but overwritten after the
                //  next chunk's phase A + syncthreads — harmless by design.)
                const unsigned short* Hr = Gs + ((p ^ 1) << 10) + rbase;
                g0 = *(const f16x8*)(Hr);
                g1 = *(const f16x8*)(Hr + 512);
                ihacc = *(const floatx4*)&IH[(s + 1) & (CHT - 1)][nt][ihoff];
            }
        }
    }

    // ---- Head: out[b] = sum_u wfc[u] * h[u][b] + b_fc ----
    float acc = wfcv[0] * hv[0] + wfcv[1] * hv[1] + wfcv[2] * hv[2] + wfcv[3] * hv[3];
    acc += __shfl_xor(acc, 16, 64);
    acc += __shfl_xor(acc, 32, 64);
    if (qd == 0) Ps[nt * 16 + ln] = acc;
    __syncthreads();
    if (tid < 16)
        out[b0 + tid] = Ps[tid] + Ps[16 + tid] + Ps[32 + tid] + Ps[48 + tid] + b_fc[0];
}

extern "C" void kernel_launch(void* const* d_in, const int* in_sizes, int n_in,
                              void* d_out, int out_size, void* d_ws, size_t ws_size,
                              hipStream_t stream) {
    const float* x    = (const float*)d_in[0];
    const float* W_ih = (const float*)d_in[1];
    const float* W_hh = (const float*)d_in[2];
    const float* b_ih = (const float*)d_in[3];
    const float* b_hh = (const float*)d_in[4];
    const float* W_fc = (const float*)d_in[5];
    const float* b_fc = (const float*)d_in[6];
    float* out = (float*)d_out;

    // 256 tiles of 16 chains; 4 waves/block (one per SIMD), 1 block per CU.
    rnn_2ph16_kernel<<<dim3(BATCH / 16), dim3(256), 0, stream>>>(
        x, W_ih, W_hh, b_ih, b_hh, W_fc, b_fc, out);
}

// Round 10
// 251.507 us; speedup vs baseline: 1.1186x; 1.0077x over previous
//
#include <hip/hip_runtime.h>

#define INPUT 32
#define HIDDEN 64
#define BATCH 4096
#define SEQ 256
#define CHT 16   // timesteps per chunk (halved: 2 blocks must share a CU)
#define COLS 8   // batch columns per chain (half-filled MFMA N)

typedef __attribute__((ext_vector_type(8))) _Float16 f16x8;   // 8 fp16 (4 VGPRs)
typedef __attribute__((ext_vector_type(2))) __fp16 cvt2_t;    // cvt_pkrtz result
typedef __attribute__((ext_vector_type(4))) float floatx4;    // 4 fp32

#define MFMA16(a, b, c) __builtin_amdgcn_mfma_f32_16x16x32_f16((a), (b), (c), 0, 0, 0)

// LDS-only barrier: wait LDS ops, leave global loads in flight.
#define LDS_BARRIER() asm volatile("s_waitcnt lgkmcnt(0)\n\ts_barrier" ::: "memory")

union FragH { f16x8 v; unsigned u[4]; unsigned short s[8]; };

// v_cvt_pkrtz_f16_f32: packs (a,b) -> (lo,hi) fp16 RTZ, as a u32 word.
__device__ __forceinline__ unsigned pkrtz(float a, float b) {
    cvt2_t r = __builtin_amdgcn_cvt_pkrtz(a, b);
    union { cvt2_t v; unsigned u; } c; c.v = r; return c.u;
}

// f32 -> fp16 RNE (setup-only, for weights).
__device__ __forceinline__ unsigned short f2h(float f) {
    _Float16 h = (_Float16)f;                 // v_cvt_f16_f32, RNE
    union { _Float16 h; unsigned short s; } c; c.h = h; return c.s;
}
__device__ __forceinline__ void cvt8(const float f[8], FragH& out) {
#pragma unroll
    for (int j = 0; j < 8; ++j) out.s[j] = f2h(f[j]);
}

// Round-22: 2 chains/CU. r21 (fp16, hoisted ih) runs Phase B at ~946cy/step
// with Occupancy 10.9% — each SIMD hosts ONE wave that is >=50% stalled
// (ds_write drain -> barrier -> ds_read latency -> MFMA latency -> tanh
// transcendental latency). Those stalls are dead issue slots. This round
// co-schedules a SECOND independent chain on the same SIMDs: 512 chains of
// 8 batch columns (MFMA N half-empty — MFMA count was never the wall),
// 512 blocks, 2 blocks/CU (LDS halved via CHT 32->16: 64K IH + 4K Gs =
// ~69K/block; VGPR 132 <= 256 -> 2 waves/SIMD fit). While chain A waits on
// its barrier/LDS/trans latency, chain B issues — stalls overlap.
// Lanes ln>=8 duplicate column ln&7 (same x addresses -> L1 broadcast; no
// OOB; MFMA columns are independent) -> surviving columns' math is
// BIT-IDENTICAL to r21: absmax must reproduce 0.00390625 exactly.
// Diagnostic: OccupancyPercent must ~double to ~21; if it does and dur is
// flat, chains serialize on shared LDS/barrier resources -> revert.
// Layouts (verified r5-r21): C/D row(m)=4qd+r, col(n)=ln. A: m=ln, k=8qd+j
//   (+32kt). B: n=ln, k=8qd+j (+32kt). G in LDS (u16 payload, fp16):
//   buf*1024 + kt*512 + ln*32 + slot*8 + j, slot=(qd+(ln>>1))&3.
// IH layout: IH[s][mt][(qd*16+ln)*4 + r] f32 (exact detour, r18-verified).
__global__ __launch_bounds__(256, 2) void rnn_2x16_kernel(
    const float* __restrict__ x,     // [B, T, 32]
    const float* __restrict__ W_ih,  // [64, 32]
    const float* __restrict__ W_hh,  // [64, 64]
    const float* __restrict__ b_ih,  // [64]
    const float* __restrict__ b_hh,  // [64]
    const float* __restrict__ W_fc,  // [1, 64]
    const float* __restrict__ b_fc,  // [1]
    float* __restrict__ out)         // [B, 1]
{
    const int tid  = threadIdx.x;
    const int nt   = tid >> 6;        // wave id: owns hidden rows [16nt, 16nt+16)
    const int lane = tid & 63;
    const int ln   = lane & 15;
    const int qd   = lane >> 4;
    const int b0   = blockIdx.x * COLS;

    __shared__ __align__(16) float IH[CHT][4][256];         // 64 KiB ih buffer
    __shared__ __align__(16) unsigned short Gs[2048];       // 4 KiB: 2 bufs
    __shared__ float Ps[64];

    { // zero G buffer 0 (h_{-1} = 0); visible after first phase-A sync
        unsigned* z = (unsigned*)Gs;
        for (int i = tid; i < 512; i += 256) z[i] = 0u;
    }

    // ---- Static weights (fp16 RNE) ----
    FragH WihF[4], WhhF[2];
    floatx4 bbv4[4];
    {
        float f[8];
#pragma unroll
        for (int mt = 0; mt < 4; ++mt) {
            const float* ri = W_ih + (mt * 16 + ln) * INPUT + qd * 8;
            *(float4*)&f[0] = *(const float4*)ri;
            *(float4*)&f[4] = *(const float4*)(ri + 4);
            cvt8(f, WihF[mt]);
            float4 bi = *(const float4*)(b_ih + mt * 16 + qd * 4);
            float4 bh = *(const float4*)(b_hh + mt * 16 + qd * 4);
            bbv4[mt][0] = bi.x + bh.x; bbv4[mt][1] = bi.y + bh.y;
            bbv4[mt][2] = bi.z + bh.z; bbv4[mt][3] = bi.w + bh.w;
        }
        const float* rh = W_hh + (nt * 16 + ln) * HIDDEN + qd * 8;
#pragma unroll
        for (int kt = 0; kt < 2; ++kt) {
            *(float4*)&f[0] = *(const float4*)(rh + kt * 32);
            *(float4*)&f[4] = *(const float4*)(rh + kt * 32 + 4);
            cvt8(f, WhhF[kt]);
        }
    }
    const int u0 = nt * 16 + qd * 4;   // this lane's 4 output rows (phase B)
    floatx4 wfcv;
    {
        float4 wf = *(const float4*)(W_fc + u0);
        wfcv[0] = wf.x; wfcv[1] = wf.y; wfcv[2] = wf.z; wfcv[3] = wf.w;
    }

    // Exchange bases (r12/r18, verified): reader (B-frag) and writer.
    const int rbase = ln * 32 + ((qd + (ln >> 1)) & 3) * 8;
    const int wbase = (u0 >> 5) * 512 + ln * 32 +
                      ((((u0 >> 3) & 3) + (ln >> 1)) & 3) * 8 + (u0 & 7);

    // Lanes ln>=8 duplicate column ln&7 (no OOB; L1 broadcast).
    const float* xp = x + (size_t)(b0 + (ln & 7)) * (SEQ * INPUT) + qd * 8;
    const int ihoff = (qd * 16 + ln) * 4;   // this lane's float4 in a slab

    f16x8 g0, g1;
    floatx4 ihacc;
    float hv[4];

#pragma unroll 1
    for (int cb = 0; cb < SEQ; cb += CHT) {
        // ================= Phase A: ih for t in [cb, cb+CHT) =================
        {
            const int tbase = cb + nt * (CHT / 4);
#pragma unroll
            for (int i = 0; i < CHT / 4; ++i) {
                const int t = tbase + i;
                float4 ra = *(const float4*)(xp + t * INPUT);
                float4 rb = *(const float4*)(xp + t * INPUT + 4);
                FragH X;
                X.u[0] = pkrtz(ra.x, ra.y);
                X.u[1] = pkrtz(ra.z, ra.w);
                X.u[2] = pkrtz(rb.x, rb.y);
                X.u[3] = pkrtz(rb.z, rb.w);
#pragma unroll
                for (int mt = 0; mt < 4; ++mt) {
                    floatx4 ih = MFMA16(WihF[mt].v, X.v, bbv4[mt]);
                    *(floatx4*)&IH[t - cb][mt][ihoff] = ih;
                }
            }
        }
        __syncthreads();   // IH chunk + (first iter) zero-init visible

        if (cb == 0) {     // initial g = h_{-1} = 0 from G buffer 0
            g0 = *(const f16x8*)(Gs + rbase);
            g1 = *(const f16x8*)(Gs + rbase + 512);
        }
        ihacc = *(const floatx4*)&IH[0][nt][ihoff];

        // ================= Phase B: CHT serial steps =================
#pragma unroll 1
        for (int sb = 0; sb < CHT; sb += 2) {
#pragma unroll
            for (int p = 0; p < 2; ++p) {
                const int s = sb + p;   // parity p == s&1 (t = cb+s, cb%16==0)

                // hh critical path: single fp16 depth-2 chain.
                floatx4 a = MFMA16(WhhF[0].v, g0, ihacc);
                a = MFMA16(WhhF[1].v, g1, a);

                // tanh of this wave's 4 elements.
#pragma unroll
                for (int r = 0; r < 4; ++r) {
                    float pv = a[r];
                    float e = __expf(2.0f * pv);
                    hv[r] = 1.0f - 2.0f * __builtin_amdgcn_rcpf(e + 1.0f);
                }

                // Pack 4 -> 2 u32, ONE ds_write_b64.
                uint2 wv;
                wv.x = pkrtz(hv[0], hv[1]);
                wv.y = pkrtz(hv[2], hv[3]);
                *(uint2*)(Gs + ((p ^ 1) << 10) + wbase) = wv;

                LDS_BARRIER();   // publish h_t; nothing else on lgkm queue

                // Prefetch g for t+1 and ihacc for s+1.
                // (s==CHT-1: IH read is stale but re-loaded after the next
                //  chunk's phase A + syncthreads — harmless by design.)
                const unsigned short* Hr = Gs + ((p ^ 1) << 10) + rbase;
                g0 = *(const f16x8*)(Hr);
                g1 = *(const f16x8*)(Hr + 512);
                ihacc = *(const floatx4*)&IH[(s + 1) & (CHT - 1)][nt][ihoff];
            }
        }
    }

    // ---- Head: out[b] = sum_u wfc[u] * h[u][b] + b_fc ----
    float acc = wfcv[0] * hv[0] + wfcv[1] * hv[1] + wfcv[2] * hv[2] + wfcv[3] * hv[3];
    acc += __shfl_xor(acc, 16, 64);
    acc += __shfl_xor(acc, 32, 64);
    if (qd == 0) Ps[nt * 16 + ln] = acc;
    __syncthreads();
    if (tid < COLS)
        out[b0 + tid] = Ps[tid] + Ps[16 + tid] + Ps[32 + tid] + Ps[48 + tid] + b_fc[0];
}

extern "C" void kernel_launch(void* const* d_in, const int* in_sizes, int n_in,
                              void* d_out, int out_size, void* d_ws, size_t ws_size,
                              hipStream_t stream) {
    const float* x    = (const float*)d_in[0];
    const float* W_ih = (const float*)d_in[1];
    const float* W_hh = (const float*)d_in[2];
    const float* b_ih = (const float*)d_in[3];
    const float* b_hh = (const float*)d_in[4];
    const float* W_fc = (const float*)d_in[5];
    const float* b_fc = (const float*)d_in[6];
    float* out = (float*)d_out;

    // 512 chains of 8 batch cols; 4 waves/block; 2 blocks (chains) per CU —
    // independent chains interleave into each other's stall slots.
    rnn_2x16_kernel<<<dim3(BATCH / COLS), dim3(256), 0, stream>>>(
        x, W_ih, W_hh, b_ih, b_hh, W_fc, b_fc, out);
}